// Round 1
// baseline (714.444 us; speedup 1.0000x reference)
//
#include <hip/hip_runtime.h>
#include <math.h>

#define TB 4
#define TN 2000
#define TK 30
#define TH 128
#define TNIN 256
#define TDFF 512
#define NTOK (TB*TN)

constexpr float LN_EPS = 1e-6f;
constexpr float NEG_INF = -3.402823466e38f;
constexpr float INV_SQRT_D = 0.17677669529663687f;  // 1/sqrt(32)

// ---------------------------------------------------------------------------
// K1: per-token fused  KV-projection -> attention -> W_O -> residual -> LN0
// grid = 8000 blocks, 256 threads.
// LDS: he[32][256] (h_e tile, reused as [Kp|Vp]) + wch[16][256] (weights,
// i-major) ~= 52KB -> 3 blocks/CU.
// ---------------------------------------------------------------------------
__global__ __launch_bounds__(256) void attn_kernel(
    const float* __restrict__ h_v, const float* __restrict__ h_e,
    const float* __restrict__ mask_attend,
    const float* __restrict__ W_Q, const float* __restrict__ W_K,
    const float* __restrict__ W_V, const float* __restrict__ W_O,
    const float* __restrict__ gain0, const float* __restrict__ bias0,
    float* __restrict__ Hn)
{
  const int bn  = blockIdx.x;
  const int tid = threadIdx.x;

  __shared__ float he[32][256];   // h_e tile; after projection reused as kv: cols 0..127 Kp, 128..255 Vp
  __shared__ float wch[16][256];  // weight chunk, i-major: wch[i_local][j]
  __shared__ float hv[128];
  __shared__ float qv[128];
  __shared__ float lg[4][32];
  __shared__ float att[4][32];
  __shared__ float ul[128];
  __shared__ float xr[128];
  __shared__ float red[2];

  // ---- stage h_e tile (rows 30,31 zero-padded), h_v row ----
  for (int t = tid; t < 32*64; t += 256) {
    int row = t >> 6, i4 = t & 63;
    float4 v = make_float4(0.f,0.f,0.f,0.f);
    if (row < TK) v = *(const float4*)&h_e[((size_t)bn*TK + row)*TNIN + i4*4];
    *(float4*)&he[row][i4*4] = v;
  }
  if (tid < 32) *(float4*)&hv[tid*4] = *(const float4*)&h_v[(size_t)bn*TH + tid*4];
  __syncthreads();

  // ---- Q = h_v_row @ W_Q^T  (threads 0..127, one output each) ----
  if (tid < TH) {
    const float* wq = W_Q + tid*TH;
    float a = 0.f;
    #pragma unroll
    for (int i = 0; i < TH; i += 4) {
      float4 w = *(const float4*)(wq + i);
      a += hv[i]*w.x + hv[i+1]*w.y + hv[i+2]*w.z + hv[i+3]*w.w;
    }
    qv[tid] = a;
  }

  // ---- KV projection: acc[r][c] = sum_i he[kg*8+r][i] * Wcomb[jg*4+c][i] ----
  // thread (kg=tid>>6, jg=tid&63): 8 k-rows x 4 combined-cols register tile.
  const int kg = tid >> 6, jg = tid & 63;
  float acc[8][4];
  #pragma unroll
  for (int r=0;r<8;r++){
    #pragma unroll
    for (int c=0;c<4;c++) acc[r][c]=0.f;
  }

  for (int c0 = 0; c0 < TNIN; c0 += 16) {
    __syncthreads();  // protect previous chunk's reads
    // stage 16-i x 256-j weight chunk, i-major (conflict-free writes: lanes = consecutive j)
    for (int t = tid; t < 1024; t += 256) {
      int j = t & 255, ii4 = t >> 8;
      const float* src = (j < TH) ? &W_K[(size_t)j*TNIN + c0 + ii4*4]
                                  : &W_V[(size_t)(j-TH)*TNIN + c0 + ii4*4];
      float4 w = *(const float4*)src;
      wch[ii4*4+0][j] = w.x; wch[ii4*4+1][j] = w.y;
      wch[ii4*4+2][j] = w.z; wch[ii4*4+3][j] = w.w;
    }
    __syncthreads();
    #pragma unroll
    for (int i4 = 0; i4 < 4; ++i4) {
      float ar[8][4];
      #pragma unroll
      for (int r=0;r<8;r++) {   // broadcast b128 reads (all lanes in wave share kg)
        float4 tv = *(const float4*)&he[kg*8+r][c0 + i4*4];
        ar[r][0]=tv.x; ar[r][1]=tv.y; ar[r][2]=tv.z; ar[r][3]=tv.w;
      }
      #pragma unroll
      for (int d=0; d<4; ++d) { // stride-4 b128 reads, conflict-free
        float4 wv = *(const float4*)&wch[i4*4+d][jg*4];
        #pragma unroll
        for (int r=0;r<8;r++) {
          acc[r][0] += ar[r][d]*wv.x;
          acc[r][1] += ar[r][d]*wv.y;
          acc[r][2] += ar[r][d]*wv.z;
          acc[r][3] += ar[r][d]*wv.w;
        }
      }
    }
  }
  __syncthreads();  // all he reads done -> safe to overwrite with kv
  #pragma unroll
  for (int r=0;r<8;r++){
    int k = kg*8 + r;
    if (k < TK)
      *(float4*)&he[k][jg*4] = make_float4(acc[r][0],acc[r][1],acc[r][2],acc[r][3]);
  }
  __syncthreads();

  // ---- logits (lane rotation kills the stride-256 bank conflict) ----
  if (tid < TH) {
    int hh = tid >> 5, kk = tid & 31;
    float val = NEG_INF;
    if (kk < TK) {
      float s = 0.f;
      #pragma unroll
      for (int dd=0; dd<32; ++dd) {
        int d = (dd + kk) & 31;
        s += qv[hh*32+d] * he[kk][hh*32+d];
      }
      float ma = mask_attend[(size_t)bn*TK + kk];
      val = (ma > 0.f) ? s*INV_SQRT_D : NEG_INF;
    }
    lg[hh][kk] = val;
  }
  __syncthreads();

  // ---- softmax per head (tiny: 4 lanes, 30 iters) ----
  if (tid < 4) {
    float m = NEG_INF;
    for (int k=0;k<TK;k++) m = fmaxf(m, lg[tid][k]);
    float s = 0.f;
    for (int k=0;k<TK;k++){ float e = expf(lg[tid][k]-m); att[tid][k]=e; s+=e; }
    float inv = 1.f/s;
    for (int k=0;k<TK;k++) att[tid][k] *= inv;
  }
  __syncthreads();

  // ---- h_upd = attend @ Vp ----
  if (tid < TH) {
    int hh = tid >> 5;
    float u = 0.f;
    for (int k=0;k<TK;k++) u += att[hh][k]*he[k][TH+tid];
    ul[tid] = u;
  }
  __syncthreads();

  // ---- dh = h_upd @ W_O^T ; residual ----
  if (tid < TH) {
    const float* wo = W_O + tid*TH;
    float dsum = 0.f;
    #pragma unroll
    for (int i=0;i<TH;i+=4){
      float4 w = *(const float4*)(wo+i);
      dsum += ul[i]*w.x + ul[i+1]*w.y + ul[i+2]*w.z + ul[i+3]*w.w;
    }
    xr[tid] = hv[tid] + dsum;
  }
  __syncthreads();

  // ---- LayerNorm0 (ddof=1, double-eps, exactly like reference) ----
  if (tid < 64) {
    float v1 = xr[tid], v2 = xr[tid+64];
    float s1 = v1+v2, s2 = v1*v1 + v2*v2;
    #pragma unroll
    for (int m=32; m>=1; m>>=1){ s1 += __shfl_down(s1,m); s2 += __shfl_down(s2,m); }
    if (tid==0){
      float mu  = s1*(1.f/128.f);
      float var = (s2 - 128.f*mu*mu)*(1.f/127.f);
      float inv = 1.f/(sqrtf(var+LN_EPS)+LN_EPS);
      red[0]=mu; red[1]=inv;
    }
  }
  __syncthreads();
  if (tid < TH) {
    float hn = gain0[tid]*(xr[tid]-red[0])*red[1] + bias0[tid];
    Hn[(size_t)bn*TH + tid] = hn;
  }
}

// ---------------------------------------------------------------------------
// K2: Z = relu(Hn @ W_in^T + b_in)   [8000x128]@[128x512]
// block = 32 tokens x 128 cols, grid (250,4). LDS 80KB -> 2 blocks/CU.
// ---------------------------------------------------------------------------
__global__ __launch_bounds__(256) void ffn1_kernel(
    const float* __restrict__ Hn, const float* __restrict__ W_in,
    const float* __restrict__ b_in, float* __restrict__ Z)
{
  const int tid  = threadIdx.x;
  const int tok0 = blockIdx.x * 32;
  const int f0   = blockIdx.y * 128;
  __shared__ float A[32][128];
  __shared__ float Wt[128][128];  // i-major: Wt[i][f_local]

  for (int t = tid; t < 32*32; t += 256) {
    int row = t >> 5, i4 = t & 31;
    *(float4*)&A[row][i4*4] = *(const float4*)&Hn[(size_t)(tok0+row)*TH + i4*4];
  }
  for (int t = tid; t < 128*32; t += 256) {
    int f = t & 127, i4 = t >> 7;
    float4 w = *(const float4*)&W_in[(size_t)(f0+f)*TH + i4*4];
    Wt[i4*4+0][f]=w.x; Wt[i4*4+1][f]=w.y; Wt[i4*4+2][f]=w.z; Wt[i4*4+3][f]=w.w;
  }
  __syncthreads();

  const int tokg = tid>>5, colg = tid&31;
  float acc[4][4] = {};
  for (int i=0;i<TH;i+=4){
    float a[4][4];
    #pragma unroll
    for (int r=0;r<4;r++){
      float4 tv=*(const float4*)&A[tokg*4+r][i];
      a[r][0]=tv.x;a[r][1]=tv.y;a[r][2]=tv.z;a[r][3]=tv.w;
    }
    #pragma unroll
    for (int d=0; d<4; ++d){
      float4 wv = *(const float4*)&Wt[i+d][colg*4];
      #pragma unroll
      for (int r=0;r<4;r++){
        acc[r][0]+=a[r][d]*wv.x; acc[r][1]+=a[r][d]*wv.y;
        acc[r][2]+=a[r][d]*wv.z; acc[r][3]+=a[r][d]*wv.w;
      }
    }
  }
  float4 bv = *(const float4*)&b_in[f0 + colg*4];
  #pragma unroll
  for (int r=0;r<4;r++){
    float4 z;
    z.x = fmaxf(acc[r][0]+bv.x, 0.f);
    z.y = fmaxf(acc[r][1]+bv.y, 0.f);
    z.z = fmaxf(acc[r][2]+bv.z, 0.f);
    z.w = fmaxf(acc[r][3]+bv.w, 0.f);
    *(float4*)&Z[(size_t)(tok0+tokg*4+r)*TDFF + f0 + colg*4] = z;
  }
}

// ---------------------------------------------------------------------------
// K3: out = mask_v * LN1(Hn + Z @ W_out^T + b_out)   [8000x512]@[512x128]
// block = 32 tokens x full 128 cols (LN needs the whole row), grid 250.
// ---------------------------------------------------------------------------
__global__ __launch_bounds__(256) void ffn2_kernel(
    const float* __restrict__ Z, const float* __restrict__ W_out,
    const float* __restrict__ b_out, const float* __restrict__ Hn,
    const float* __restrict__ gain1, const float* __restrict__ bias1,
    const float* __restrict__ mask_v, float* __restrict__ out)
{
  const int tid  = threadIdx.x;
  const int tok0 = blockIdx.x * 32;
  __shared__ float A[32][128];
  __shared__ float Wt[128][128];

  const int tokg = tid>>5, colg = tid&31;
  float acc[4][4] = {};

  for (int c=0;c<4;++c){
    __syncthreads();
    for (int t = tid; t < 32*32; t += 256){
      int row = t>>5, i4 = t&31;
      *(float4*)&A[row][i4*4] = *(const float4*)&Z[(size_t)(tok0+row)*TDFF + c*128 + i4*4];
    }
    for (int t = tid; t < 128*32; t += 256){
      int j = t & 127, i4 = t >> 7;
      float4 w = *(const float4*)&W_out[(size_t)j*TDFF + c*128 + i4*4];
      Wt[i4*4+0][j]=w.x; Wt[i4*4+1][j]=w.y; Wt[i4*4+2][j]=w.z; Wt[i4*4+3][j]=w.w;
    }
    __syncthreads();
    for (int i=0;i<128;i+=4){
      float a[4][4];
      #pragma unroll
      for (int r=0;r<4;r++){
        float4 tv=*(const float4*)&A[tokg*4+r][i];
        a[r][0]=tv.x;a[r][1]=tv.y;a[r][2]=tv.z;a[r][3]=tv.w;
      }
      #pragma unroll
      for (int d=0; d<4; ++d){
        float4 wv = *(const float4*)&Wt[i+d][colg*4];
        #pragma unroll
        for (int r=0;r<4;r++){
          acc[r][0]+=a[r][d]*wv.x; acc[r][1]+=a[r][d]*wv.y;
          acc[r][2]+=a[r][d]*wv.z; acc[r][3]+=a[r][d]*wv.w;
        }
      }
    }
  }

  float4 bo = *(const float4*)&b_out[colg*4];
  float4 g  = *(const float4*)&gain1[colg*4];
  float4 bb = *(const float4*)&bias1[colg*4];
  #pragma unroll
  for (int r=0;r<4;r++){
    int tok = tok0 + tokg*4 + r;
    float4 hn = *(const float4*)&Hn[(size_t)tok*TH + colg*4];
    float x0 = acc[r][0]+bo.x+hn.x;
    float x1 = acc[r][1]+bo.y+hn.y;
    float x2 = acc[r][2]+bo.z+hn.z;
    float x3 = acc[r][3]+bo.w+hn.w;
    float s1 = x0+x1+x2+x3;
    float s2 = x0*x0+x1*x1+x2*x2+x3*x3;
    #pragma unroll
    for (int m=16;m>=1;m>>=1){ s1 += __shfl_xor(s1,m,32); s2 += __shfl_xor(s2,m,32); }
    float mu  = s1*(1.f/128.f);
    float var = (s2 - 128.f*mu*mu)*(1.f/127.f);
    float inv = 1.f/(sqrtf(var+LN_EPS)+LN_EPS);
    float mv  = mask_v[tok];
    float4 y;
    y.x = mv*(g.x*(x0-mu)*inv + bb.x);
    y.y = mv*(g.y*(x1-mu)*inv + bb.y);
    y.z = mv*(g.z*(x2-mu)*inv + bb.z);
    y.w = mv*(g.w*(x3-mu)*inv + bb.w);
    *(float4*)&out[(size_t)tok*TH + colg*4] = y;
  }
}

// ---------------------------------------------------------------------------
extern "C" void kernel_launch(void* const* d_in, const int* in_sizes, int n_in,
                              void* d_out, int out_size, void* d_ws, size_t ws_size,
                              hipStream_t stream)
{
  const float* h_v         = (const float*)d_in[0];
  const float* h_e         = (const float*)d_in[1];
  const float* mask_v      = (const float*)d_in[2];
  const float* mask_attend = (const float*)d_in[3];
  const float* W_Q   = (const float*)d_in[4];
  const float* W_K   = (const float*)d_in[5];
  const float* W_V   = (const float*)d_in[6];
  const float* W_O   = (const float*)d_in[7];
  const float* gain0 = (const float*)d_in[8];
  const float* bias0 = (const float*)d_in[9];
  const float* gain1 = (const float*)d_in[10];
  const float* bias1 = (const float*)d_in[11];
  const float* W_in  = (const float*)d_in[12];
  const float* b_in  = (const float*)d_in[13];
  const float* W_out = (const float*)d_in[14];
  const float* b_out = (const float*)d_in[15];

  float* out = (float*)d_out;
  float* Hn  = (float*)d_ws;                    // 8000*128 f32 = 4.1 MB
  float* Z   = Hn + (size_t)NTOK*TH;            // 8000*512 f32 = 16.4 MB

  attn_kernel<<<NTOK, 256, 0, stream>>>(h_v, h_e, mask_attend, W_Q, W_K, W_V,
                                        W_O, gain0, bias0, Hn);
  ffn1_kernel<<<dim3(NTOK/32, TDFF/128), 256, 0, stream>>>(Hn, W_in, b_in, Z);
  ffn2_kernel<<<NTOK/32, 256, 0, stream>>>(Z, W_out, b_out, Hn, gain1, bias1,
                                           mask_v, out);
}

// Round 2
// 422.415 us; speedup vs baseline: 1.6913x; 1.6913x over previous
//
#include <hip/hip_runtime.h>
#include <math.h>

#define TB 4
#define TN 2000
#define TK 30
#define TH 128
#define TNIN 256
#define TDFF 512
#define NTOK (TB*TN)

typedef __attribute__((ext_vector_type(8))) short short8v;
typedef __attribute__((ext_vector_type(4))) float f32x4;

constexpr float LN_EPS = 1e-6f;
constexpr float NEG_INF = -3.402823466e38f;
constexpr float INV_SQRT_D = 0.17677669529663687f;  // 1/sqrt(32)

// round-to-nearest-even f32 -> bf16 (finite inputs only)
static __device__ __forceinline__ short f2bf(float f) {
  unsigned u = __float_as_uint(f);
  u = u + 0x7fffu + ((u >> 16) & 1u);
  return (short)(u >> 16);
}

// ---------------------------------------------------------------------------
// K0: convert W_K (128x256) || W_V (128x256) -> Wc bf16 [256][256] row-major.
// Row j<128 = W_K[j], j>=128 = W_V[j-128].  grid 256 x 256thr, 1 elem each.
// ---------------------------------------------------------------------------
__global__ void conv_weights_kernel(const float* __restrict__ W_K,
                                    const float* __restrict__ W_V,
                                    unsigned short* __restrict__ Wc)
{
  int idx = blockIdx.x * 256 + threadIdx.x;   // 0..65535
  int j = idx >> 8, i = idx & 255;
  float v = (j < TH) ? W_K[(size_t)j*TNIN + i] : W_V[(size_t)(j-TH)*TNIN + i];
  Wc[idx] = (unsigned short)f2bf(v);
}

// ---------------------------------------------------------------------------
// K1: per-token fused  KV-projection (MFMA bf16) -> attention -> W_O -> LN0
// grid = 8000 blocks, 256 threads (4 waves).
// GEMM: C[32x256] = A[32x256] @ Wc^T, K in 8 steps of 32.
//   A-frags: direct from global h_e (f32, full-line coalesced), cvt->bf16.
//   B-frags: direct from global Wc (bf16, 128KB, L2-resident).
//   No LDS staging for the GEMM; acc -> kv[32][256] f32 LDS for the tail.
// ---------------------------------------------------------------------------
__global__ __launch_bounds__(256) void attn_kernel(
    const float* __restrict__ h_v, const float* __restrict__ h_e,
    const float* __restrict__ mask_attend,
    const float* __restrict__ W_Q, const unsigned short* __restrict__ Wc,
    const float* __restrict__ W_O,
    const float* __restrict__ gain0, const float* __restrict__ bias0,
    float* __restrict__ Hn)
{
  const int bn   = blockIdx.x;
  const int tid  = threadIdx.x;
  const int wave = tid >> 6;
  const int lane = tid & 63;
  const int lm   = lane & 15;   // fragment row/col
  const int lgp  = lane >> 4;   // k-group

  __shared__ float kv[32][256];   // cols 0..127 Kp, 128..255 Vp (f32)
  __shared__ float hv[128];
  __shared__ float qv[128];
  __shared__ float lgits[4][32];
  __shared__ float att[4][32];
  __shared__ float ul[128];
  __shared__ float xr[128];
  __shared__ float red[2];

  if (tid < 32) *(float4*)&hv[tid*4] = *(const float4*)&h_v[(size_t)bn*TH + tid*4];
  __syncthreads();

  // ---- Q = h_v_row @ W_Q^T  (threads 0..127; qv consumed after next sync) ----
  if (tid < TH) {
    const float* wq = W_Q + (size_t)tid*TH;
    float a = 0.f;
    #pragma unroll
    for (int i = 0; i < TH; i += 4) {
      float4 w = *(const float4*)(wq + i);
      a += hv[i]*w.x + hv[i+1]*w.y + hv[i+2]*w.z + hv[i+3]*w.w;
    }
    qv[tid] = a;
  }

  // ---- KV projection via MFMA ----
  // wave handles cols [wave*64, wave*64+64): 4 N-tiles; M-tiles m0 = {0,16}.
  // A lane row (M-tile 1) clamped to 29: rows 30,31 are junk, never consumed.
  f32x4 acc[2][4] = {};

  const float* a0p = h_e + ((size_t)bn*TK + lm) * TNIN + lgp*8;
  int r1 = 16 + lm; if (r1 > TK-1) r1 = TK-1;
  const float* a1p = h_e + ((size_t)bn*TK + r1) * TNIN + lgp*8;
  const unsigned short* bp0 = Wc + ((size_t)(wave*64 + lm))*TNIN + lgp*8;

  #pragma unroll
  for (int kk = 0; kk < 8; ++kk) {
    const int i0 = kk*32;
    short8v a0, a1;
    {
      float4 lo = *(const float4*)(a0p + i0);
      float4 hi = *(const float4*)(a0p + i0 + 4);
      a0[0]=f2bf(lo.x); a0[1]=f2bf(lo.y); a0[2]=f2bf(lo.z); a0[3]=f2bf(lo.w);
      a0[4]=f2bf(hi.x); a0[5]=f2bf(hi.y); a0[6]=f2bf(hi.z); a0[7]=f2bf(hi.w);
    }
    {
      float4 lo = *(const float4*)(a1p + i0);
      float4 hi = *(const float4*)(a1p + i0 + 4);
      a1[0]=f2bf(lo.x); a1[1]=f2bf(lo.y); a1[2]=f2bf(lo.z); a1[3]=f2bf(lo.w);
      a1[4]=f2bf(hi.x); a1[5]=f2bf(hi.y); a1[6]=f2bf(hi.z); a1[7]=f2bf(hi.w);
    }
    #pragma unroll
    for (int n = 0; n < 4; ++n) {
      short8v b = *(const short8v*)(bp0 + (size_t)n*16*TNIN + i0);
      acc[0][n] = __builtin_amdgcn_mfma_f32_16x16x32_bf16(a0, b, acc[0][n], 0, 0, 0);
      acc[1][n] = __builtin_amdgcn_mfma_f32_16x16x32_bf16(a1, b, acc[1][n], 0, 0, 0);
    }
  }

  // C -> LDS: D row = lgp*4 + r, col = lm   (HW-verified mapping)
  #pragma unroll
  for (int m = 0; m < 2; ++m)
    #pragma unroll
    for (int n = 0; n < 4; ++n)
      #pragma unroll
      for (int r = 0; r < 4; ++r)
        kv[m*16 + lgp*4 + r][wave*64 + n*16 + lm] = acc[m][n][r];
  __syncthreads();

  // ---- logits (lane rotation kills the stride-256 bank conflict) ----
  if (tid < TH) {
    int hh = tid >> 5, kk = tid & 31;
    float val = NEG_INF;
    if (kk < TK) {
      float s = 0.f;
      #pragma unroll
      for (int dd = 0; dd < 32; ++dd) {
        int d = (dd + kk) & 31;
        s += qv[hh*32+d] * kv[kk][hh*32+d];
      }
      float ma = mask_attend[(size_t)bn*TK + kk];
      val = (ma > 0.f) ? s*INV_SQRT_D : NEG_INF;
    }
    lgits[hh][kk] = val;
  }
  __syncthreads();

  // ---- softmax per head ----
  if (tid < 4) {
    float m = NEG_INF;
    for (int k = 0; k < TK; k++) m = fmaxf(m, lgits[tid][k]);
    float s = 0.f;
    for (int k = 0; k < TK; k++){ float e = expf(lgits[tid][k]-m); att[tid][k]=e; s+=e; }
    float inv = 1.f/s;
    for (int k = 0; k < TK; k++) att[tid][k] *= inv;
  }
  __syncthreads();

  // ---- h_upd = attend @ Vp ----
  if (tid < TH) {
    int hh = tid >> 5;
    float u = 0.f;
    for (int k = 0; k < TK; k++) u += att[hh][k]*kv[k][TH+tid];
    ul[tid] = u;
  }
  __syncthreads();

  // ---- dh = h_upd @ W_O^T ; residual ----
  if (tid < TH) {
    const float* wo = W_O + (size_t)tid*TH;
    float dsum = 0.f;
    #pragma unroll
    for (int i = 0; i < TH; i += 4){
      float4 w = *(const float4*)(wo+i);
      dsum += ul[i]*w.x + ul[i+1]*w.y + ul[i+2]*w.z + ul[i+3]*w.w;
    }
    xr[tid] = hv[tid] + dsum;
  }
  __syncthreads();

  // ---- LayerNorm0 (ddof=1, double-eps, matches reference) ----
  if (tid < 64) {
    float v1 = xr[tid], v2 = xr[tid+64];
    float s1 = v1+v2, s2 = v1*v1 + v2*v2;
    #pragma unroll
    for (int m = 32; m >= 1; m >>= 1){ s1 += __shfl_down(s1,m); s2 += __shfl_down(s2,m); }
    if (tid == 0){
      float mu  = s1*(1.f/128.f);
      float var = (s2 - 128.f*mu*mu)*(1.f/127.f);
      float inv = 1.f/(sqrtf(var+LN_EPS)+LN_EPS);
      red[0]=mu; red[1]=inv;
    }
  }
  __syncthreads();
  if (tid < TH) {
    float hn = gain0[tid]*(xr[tid]-red[0])*red[1] + bias0[tid];
    Hn[(size_t)bn*TH + tid] = hn;
  }
}

// ---------------------------------------------------------------------------
// K2: Z = relu(Hn @ W_in^T + b_in)   [8000x128]@[128x512]
// ---------------------------------------------------------------------------
__global__ __launch_bounds__(256) void ffn1_kernel(
    const float* __restrict__ Hn, const float* __restrict__ W_in,
    const float* __restrict__ b_in, float* __restrict__ Z)
{
  const int tid  = threadIdx.x;
  const int tok0 = blockIdx.x * 32;
  const int f0   = blockIdx.y * 128;
  __shared__ float A[32][128];
  __shared__ float Wt[128][128];  // i-major: Wt[i][f_local]

  for (int t = tid; t < 32*32; t += 256) {
    int row = t >> 5, i4 = t & 31;
    *(float4*)&A[row][i4*4] = *(const float4*)&Hn[(size_t)(tok0+row)*TH + i4*4];
  }
  for (int t = tid; t < 128*32; t += 256) {
    int f = t & 127, i4 = t >> 7;
    float4 w = *(const float4*)&W_in[(size_t)(f0+f)*TH + i4*4];
    Wt[i4*4+0][f]=w.x; Wt[i4*4+1][f]=w.y; Wt[i4*4+2][f]=w.z; Wt[i4*4+3][f]=w.w;
  }
  __syncthreads();

  const int tokg = tid>>5, colg = tid&31;
  float acc[4][4] = {};
  for (int i = 0; i < TH; i += 4){
    float a[4][4];
    #pragma unroll
    for (int r=0;r<4;r++){
      float4 tv=*(const float4*)&A[tokg*4+r][i];
      a[r][0]=tv.x;a[r][1]=tv.y;a[r][2]=tv.z;a[r][3]=tv.w;
    }
    #pragma unroll
    for (int d=0; d<4; ++d){
      float4 wv = *(const float4*)&Wt[i+d][colg*4];
      #pragma unroll
      for (int r=0;r<4;r++){
        acc[r][0]+=a[r][d]*wv.x; acc[r][1]+=a[r][d]*wv.y;
        acc[r][2]+=a[r][d]*wv.z; acc[r][3]+=a[r][d]*wv.w;
      }
    }
  }
  float4 bv = *(const float4*)&b_in[f0 + colg*4];
  #pragma unroll
  for (int r=0;r<4;r++){
    float4 z;
    z.x = fmaxf(acc[r][0]+bv.x, 0.f);
    z.y = fmaxf(acc[r][1]+bv.y, 0.f);
    z.z = fmaxf(acc[r][2]+bv.z, 0.f);
    z.w = fmaxf(acc[r][3]+bv.w, 0.f);
    *(float4*)&Z[(size_t)(tok0+tokg*4+r)*TDFF + f0 + colg*4] = z;
  }
}

// ---------------------------------------------------------------------------
// K3: out = mask_v * LN1(Hn + Z @ W_out^T + b_out)
// ---------------------------------------------------------------------------
__global__ __launch_bounds__(256) void ffn2_kernel(
    const float* __restrict__ Z, const float* __restrict__ W_out,
    const float* __restrict__ b_out, const float* __restrict__ Hn,
    const float* __restrict__ gain1, const float* __restrict__ bias1,
    const float* __restrict__ mask_v, float* __restrict__ out)
{
  const int tid  = threadIdx.x;
  const int tok0 = blockIdx.x * 32;
  __shared__ float A[32][128];
  __shared__ float Wt[128][128];

  const int tokg = tid>>5, colg = tid&31;
  float acc[4][4] = {};

  for (int c = 0; c < 4; ++c){
    __syncthreads();
    for (int t = tid; t < 32*32; t += 256){
      int row = t>>5, i4 = t&31;
      *(float4*)&A[row][i4*4] = *(const float4*)&Z[(size_t)(tok0+row)*TDFF + c*128 + i4*4];
    }
    for (int t = tid; t < 128*32; t += 256){
      int j = t & 127, i4 = t >> 7;
      float4 w = *(const float4*)&W_out[(size_t)j*TDFF + c*128 + i4*4];
      Wt[i4*4+0][j]=w.x; Wt[i4*4+1][j]=w.y; Wt[i4*4+2][j]=w.z; Wt[i4*4+3][j]=w.w;
    }
    __syncthreads();
    for (int i = 0; i < 128; i += 4){
      float a[4][4];
      #pragma unroll
      for (int r=0;r<4;r++){
        float4 tv=*(const float4*)&A[tokg*4+r][i];
        a[r][0]=tv.x;a[r][1]=tv.y;a[r][2]=tv.z;a[r][3]=tv.w;
      }
      #pragma unroll
      for (int d=0; d<4; ++d){
        float4 wv = *(const float4*)&Wt[i+d][colg*4];
        #pragma unroll
        for (int r=0;r<4;r++){
          acc[r][0]+=a[r][d]*wv.x; acc[r][1]+=a[r][d]*wv.y;
          acc[r][2]+=a[r][d]*wv.z; acc[r][3]+=a[r][d]*wv.w;
        }
      }
    }
  }

  float4 bo = *(const float4*)&b_out[colg*4];
  float4 g  = *(const float4*)&gain1[colg*4];
  float4 bb = *(const float4*)&bias1[colg*4];
  #pragma unroll
  for (int r=0;r<4;r++){
    int tok = tok0 + tokg*4 + r;
    float4 hn = *(const float4*)&Hn[(size_t)tok*TH + colg*4];
    float x0 = acc[r][0]+bo.x+hn.x;
    float x1 = acc[r][1]+bo.y+hn.y;
    float x2 = acc[r][2]+bo.z+hn.z;
    float x3 = acc[r][3]+bo.w+hn.w;
    float s1 = x0+x1+x2+x3;
    float s2 = x0*x0+x1*x1+x2*x2+x3*x3;
    #pragma unroll
    for (int m=16;m>=1;m>>=1){ s1 += __shfl_xor(s1,m,32); s2 += __shfl_xor(s2,m,32); }
    float mu  = s1*(1.f/128.f);
    float var = (s2 - 128.f*mu*mu)*(1.f/127.f);
    float inv = 1.f/(sqrtf(var+LN_EPS)+LN_EPS);
    float mv  = mask_v[tok];
    float4 y;
    y.x = mv*(g.x*(x0-mu)*inv + bb.x);
    y.y = mv*(g.y*(x1-mu)*inv + bb.y);
    y.z = mv*(g.z*(x2-mu)*inv + bb.z);
    y.w = mv*(g.w*(x3-mu)*inv + bb.w);
    *(float4*)&out[(size_t)tok*TH + colg*4] = y;
  }
}

// ---------------------------------------------------------------------------
extern "C" void kernel_launch(void* const* d_in, const int* in_sizes, int n_in,
                              void* d_out, int out_size, void* d_ws, size_t ws_size,
                              hipStream_t stream)
{
  const float* h_v         = (const float*)d_in[0];
  const float* h_e         = (const float*)d_in[1];
  const float* mask_v      = (const float*)d_in[2];
  const float* mask_attend = (const float*)d_in[3];
  const float* W_Q   = (const float*)d_in[4];
  const float* W_K   = (const float*)d_in[5];
  const float* W_V   = (const float*)d_in[6];
  const float* W_O   = (const float*)d_in[7];
  const float* gain0 = (const float*)d_in[8];
  const float* bias0 = (const float*)d_in[9];
  const float* gain1 = (const float*)d_in[10];
  const float* bias1 = (const float*)d_in[11];
  const float* W_in  = (const float*)d_in[12];
  const float* b_in  = (const float*)d_in[13];
  const float* W_out = (const float*)d_in[14];
  const float* b_out = (const float*)d_in[15];

  float* out = (float*)d_out;
  float* Hn  = (float*)d_ws;                    // 8000*128 f32
  float* Z   = Hn + (size_t)NTOK*TH;            // 8000*512 f32
  // Wc (128 KB) aliased into the head of Z: written by K0, read by K1,
  // then legally overwritten by ffn1 (stream-ordered after K1 completes).
  unsigned short* Wc = (unsigned short*)Z;

  conv_weights_kernel<<<256, 256, 0, stream>>>(W_K, W_V, Wc);
  attn_kernel<<<NTOK, 256, 0, stream>>>(h_v, h_e, mask_attend, W_Q, Wc,
                                        W_O, gain0, bias0, Hn);
  ffn1_kernel<<<dim3(NTOK/32, TDFF/128), 256, 0, stream>>>(Hn, W_in, b_in, Z);
  ffn2_kernel<<<NTOK/32, 256, 0, stream>>>(Z, W_out, b_out, Hn, gain1, bias1,
                                           mask_v, out);
}

// Round 3
// 335.840 us; speedup vs baseline: 2.1273x; 1.2578x over previous
//
#include <hip/hip_runtime.h>
#include <math.h>

#define TB 4
#define TN 2000
#define TK 30
#define TH 128
#define TNIN 256
#define TDFF 512
#define NTOK (TB*TN)

typedef __attribute__((ext_vector_type(8))) short short8v;
typedef __attribute__((ext_vector_type(4))) float f32x4;

constexpr float LN_EPS = 1e-6f;
constexpr float NEG_INF = -3.402823466e38f;
constexpr float INV_SQRT_D = 0.17677669529663687f;  // 1/sqrt(32)

// round-to-nearest-even f32 -> bf16 (finite inputs only)
static __device__ __forceinline__ short f2bf(float f) {
  unsigned u = __float_as_uint(f);
  u = u + 0x7fffu + ((u >> 16) & 1u);
  return (short)(u >> 16);
}

// async global->LDS, 16B per lane (VGPR-free deep queue)
static __device__ __forceinline__ void gload16(const void* gsrc, void* ldst) {
  __builtin_amdgcn_global_load_lds(
      (const __attribute__((address_space(1))) unsigned int*)gsrc,
      (__attribute__((address_space(3))) unsigned int*)ldst, 16, 0, 0);
}

// ---------------------------------------------------------------------------
// K0: W_K||W_V -> Wc2, bf16 in MFMA-fragment-linear order:
//   short index ((kk*16 + n)*64 + lane)*8 + j  =  Wc[n*16+(lane&15)][kk*32+(lane>>4)*8+j]
//   where Wc[r][c] = r<128 ? W_K[r][c] : W_V[r-128][c].   128 KB total.
// ---------------------------------------------------------------------------
__global__ void conv_weights_kernel(const float* __restrict__ W_K,
                                    const float* __restrict__ W_V,
                                    unsigned short* __restrict__ Wc2)
{
  int idx = blockIdx.x * 256 + threadIdx.x;   // 0..65535
  int e = idx >> 3, j = idx & 7;
  int kk = e >> 10, n = (e >> 6) & 15, lane = e & 63;
  int r = n*16 + (lane & 15);
  int c = kk*32 + (lane >> 4)*8 + j;
  float v = (r < TH) ? W_K[(size_t)r*TNIN + c] : W_V[(size_t)(r-TH)*TNIN + c];
  Wc2[idx] = (unsigned short)f2bf(v);
}

// ---------------------------------------------------------------------------
// K1: per-token fused  KV-projection (MFMA bf16, async-staged) -> attention
//     -> W_O -> residual -> LN0.   grid = 8000, 256 threads (4 waves).
// Pipeline: A (h_e f32, HBM) triple-buffered via global_load_lds with
// pre-swizzled source; B (Wc2, L2) double-buffered, fragment-linear.
// Per k-step: vmcnt(1) -> s_barrier -> issue B(k+1),A(k+2) -> ds_read+MFMA.
// ---------------------------------------------------------------------------
__global__ __launch_bounds__(256) void attn_kernel(
    const float* __restrict__ h_v, const float* __restrict__ h_e,
    const float* __restrict__ mask_attend,
    const float* __restrict__ W_Q, const unsigned short* __restrict__ Wc2,
    const float* __restrict__ W_O,
    const float* __restrict__ gain0, const float* __restrict__ bias0,
    float* __restrict__ Hn)
{
  const int bn   = blockIdx.x;
  const int tid  = threadIdx.x;
  const int wave = tid >> 6;
  const int lane = tid & 63;
  const int lm   = lane & 15;   // fragment row/col
  const int lgp  = lane >> 4;   // k-group

  __shared__ __align__(16) float kv[32][256];        // 32 KB: Kp cols 0..127, Vp 128..255
  __shared__ __align__(16) float Al[3][1024];        // 12 KB: A stage, entry t = 16B
  __shared__ __align__(16) unsigned short Bl[2][8192]; // 32 KB: B stage, frag-linear
  __shared__ float hv[128];
  __shared__ float qv[128];
  // post-GEMM scratch aliased onto dead B buffer (Bl reads all done by then)
  float* lgits = (float*)&Bl[0][0];   // [4*32]
  float* att   = lgits + 128;         // [4*32]
  float* ul    = att   + 128;         // [128]
  float* xr    = ul    + 128;         // [128]
  float* red   = xr    + 128;         // [2]

  if (tid < 32) *(float4*)&hv[tid*4] = *(const float4*)&h_v[(size_t)bn*TH + tid*4];
  __syncthreads();

  // ---- Q = h_v_row @ W_Q^T (pre-GEMM; its loads drain before the prologue) ----
  if (tid < TH) {
    const float* wq = W_Q + (size_t)tid*TH;
    float a = 0.f;
    #pragma unroll
    for (int i = 0; i < TH; i += 4) {
      float4 w = *(const float4*)(wq + i);
      a += hv[i]*w.x + hv[i+1]*w.y + hv[i+2]*w.z + hv[i+3]*w.w;
    }
    qv[tid] = a;   // consumed after post-GEMM __syncthreads
  }

  // ---- KV projection via MFMA, async-staged ----
  // A staging: thread t stages h_e[row=t>>3][colgroup (t&7)^(row&7)] (16B) at Al[buf][t*16B].
  const int rowa = tid >> 3;
  const int rowc = (rowa > TK-1) ? TK-1 : rowa;   // rows 30,31: junk (never consumed)
  const float* asrc = h_e + ((size_t)bn*TK + rowc)*TNIN + ((tid & 7) ^ (rowa & 7))*4;

  f32x4 acc[2][4] = {};

  #define ISSUE_A(K, BUF) gload16(asrc + (K)*32, &Al[BUF][tid*4])
  #define ISSUE_B(K, BUF)                                                     \
    {                                                                         \
      gload16(Wc2 + (size_t)(K)*8192 + (tid      )*8, &Bl[BUF][(tid      )*8]); \
      gload16(Wc2 + (size_t)(K)*8192 + (tid+ 256 )*8, &Bl[BUF][(tid+ 256 )*8]); \
      gload16(Wc2 + (size_t)(K)*8192 + (tid+ 512 )*8, &Bl[BUF][(tid+ 512 )*8]); \
      gload16(Wc2 + (size_t)(K)*8192 + (tid+ 768 )*8, &Bl[BUF][(tid+ 768 )*8]); \
    }

  // prologue: A(0), B(0), A(1)  -> queue [A0, B0x4, A1]
  ISSUE_A(0, 0);
  ISSUE_B(0, 0);
  ISSUE_A(1, 1);

  #pragma unroll
  for (int k = 0; k < 8; ++k) {
    // wait: step-k A and B complete (in-order counter; <=1 leaves only A(k+1))
    if (k < 7) asm volatile("s_waitcnt vmcnt(1)" ::: "memory");
    else       asm volatile("s_waitcnt vmcnt(0)" ::: "memory");
    __builtin_amdgcn_s_barrier();   // all waves' step-k loads now visible

    // prefetch (targets last read before previous barrier -> no WAR race)
    if (k < 7) ISSUE_B(k+1, (k+1)&1);
    if (k < 6) ISSUE_A(k+2, (k+2)%3);

    // A fragments from LDS (swizzled slots; 2 lanes/bank = free)
    short8v afr[2];
    #pragma unroll
    for (int m = 0; m < 2; ++m) {
      const int row = lm + m*16;
      const int s0  = row*8 + ((lgp*2    ) ^ (row & 7));
      const int s1  = row*8 + ((lgp*2 + 1) ^ (row & 7));
      float4 lo = *(const float4*)&Al[k%3][s0*4];
      float4 hi = *(const float4*)&Al[k%3][s1*4];
      afr[m][0]=f2bf(lo.x); afr[m][1]=f2bf(lo.y); afr[m][2]=f2bf(lo.z); afr[m][3]=f2bf(lo.w);
      afr[m][4]=f2bf(hi.x); afr[m][5]=f2bf(hi.y); afr[m][6]=f2bf(hi.z); afr[m][7]=f2bf(hi.w);
    }
    // B fragments: contiguous 16B/lane (conflict-free), then MFMA
    #pragma unroll
    for (int n = 0; n < 4; ++n) {
      short8v b = *(const short8v*)&Bl[k&1][(size_t)((wave*4 + n)*64 + lane)*8];
      acc[0][n] = __builtin_amdgcn_mfma_f32_16x16x32_bf16(afr[0], b, acc[0][n], 0, 0, 0);
      acc[1][n] = __builtin_amdgcn_mfma_f32_16x16x32_bf16(afr[1], b, acc[1][n], 0, 0, 0);
    }
  }
  #undef ISSUE_A
  #undef ISSUE_B

  // C -> LDS: D row = lgp*4 + r, col = lm   (HW-verified mapping, unchanged)
  #pragma unroll
  for (int m = 0; m < 2; ++m)
    #pragma unroll
    for (int n = 0; n < 4; ++n)
      #pragma unroll
      for (int r = 0; r < 4; ++r)
        kv[m*16 + lgp*4 + r][wave*64 + n*16 + lm] = acc[m][n][r];
  __syncthreads();

  // ---- logits (lane rotation kills the stride-256 bank conflict) ----
  if (tid < TH) {
    int hh = tid >> 5, kk = tid & 31;
    float val = NEG_INF;
    if (kk < TK) {
      float s = 0.f;
      #pragma unroll
      for (int dd = 0; dd < 32; ++dd) {
        int d = (dd + kk) & 31;
        s += qv[hh*32+d] * kv[kk][hh*32+d];
      }
      float ma = mask_attend[(size_t)bn*TK + kk];
      val = (ma > 0.f) ? s*INV_SQRT_D : NEG_INF;
    }
    lgits[hh*32 + kk] = val;
  }
  __syncthreads();

  // ---- softmax per head ----
  if (tid < 4) {
    float m = NEG_INF;
    for (int k = 0; k < TK; k++) m = fmaxf(m, lgits[tid*32 + k]);
    float s = 0.f;
    for (int k = 0; k < TK; k++){ float e = expf(lgits[tid*32+k]-m); att[tid*32+k]=e; s+=e; }
    float inv = 1.f/s;
    for (int k = 0; k < TK; k++) att[tid*32+k] *= inv;
  }
  __syncthreads();

  // ---- h_upd = attend @ Vp ----
  if (tid < TH) {
    int hh = tid >> 5;
    float u = 0.f;
    for (int k = 0; k < TK; k++) u += att[hh*32+k]*kv[k][TH+tid];
    ul[tid] = u;
  }
  __syncthreads();

  // ---- dh = h_upd @ W_O^T ; residual ----
  if (tid < TH) {
    const float* wo = W_O + (size_t)tid*TH;
    float dsum = 0.f;
    #pragma unroll
    for (int i = 0; i < TH; i += 4){
      float4 w = *(const float4*)(wo+i);
      dsum += ul[i]*w.x + ul[i+1]*w.y + ul[i+2]*w.z + ul[i+3]*w.w;
    }
    xr[tid] = hv[tid] + dsum;
  }
  __syncthreads();

  // ---- LayerNorm0 (ddof=1, double-eps, matches reference) ----
  if (tid < 64) {
    float v1 = xr[tid], v2 = xr[tid+64];
    float s1 = v1+v2, s2 = v1*v1 + v2*v2;
    #pragma unroll
    for (int m = 32; m >= 1; m >>= 1){ s1 += __shfl_down(s1,m); s2 += __shfl_down(s2,m); }
    if (tid == 0){
      float mu  = s1*(1.f/128.f);
      float var = (s2 - 128.f*mu*mu)*(1.f/127.f);
      float inv = 1.f/(sqrtf(var+LN_EPS)+LN_EPS);
      red[0]=mu; red[1]=inv;
    }
  }
  __syncthreads();
  if (tid < TH) {
    float hn = gain0[tid]*(xr[tid]-red[0])*red[1] + bias0[tid];
    Hn[(size_t)bn*TH + tid] = hn;
  }
}

// ---------------------------------------------------------------------------
// K2: Z = relu(Hn @ W_in^T + b_in)   [8000x128]@[128x512]
// ---------------------------------------------------------------------------
__global__ __launch_bounds__(256) void ffn1_kernel(
    const float* __restrict__ Hn, const float* __restrict__ W_in,
    const float* __restrict__ b_in, float* __restrict__ Z)
{
  const int tid  = threadIdx.x;
  const int tok0 = blockIdx.x * 32;
  const int f0   = blockIdx.y * 128;
  __shared__ float A[32][128];
  __shared__ float Wt[128][128];  // i-major: Wt[i][f_local]

  for (int t = tid; t < 32*32; t += 256) {
    int row = t >> 5, i4 = t & 31;
    *(float4*)&A[row][i4*4] = *(const float4*)&Hn[(size_t)(tok0+row)*TH + i4*4];
  }
  for (int t = tid; t < 128*32; t += 256) {
    int f = t & 127, i4 = t >> 7;
    float4 w = *(const float4*)&W_in[(size_t)(f0+f)*TH + i4*4];
    Wt[i4*4+0][f]=w.x; Wt[i4*4+1][f]=w.y; Wt[i4*4+2][f]=w.z; Wt[i4*4+3][f]=w.w;
  }
  __syncthreads();

  const int tokg = tid>>5, colg = tid&31;
  float acc[4][4] = {};
  for (int i = 0; i < TH; i += 4){
    float a[4][4];
    #pragma unroll
    for (int r=0;r<4;r++){
      float4 tv=*(const float4*)&A[tokg*4+r][i];
      a[r][0]=tv.x;a[r][1]=tv.y;a[r][2]=tv.z;a[r][3]=tv.w;
    }
    #pragma unroll
    for (int d=0; d<4; ++d){
      float4 wv = *(const float4*)&Wt[i+d][colg*4];
      #pragma unroll
      for (int r=0;r<4;r++){
        acc[r][0]+=a[r][d]*wv.x; acc[r][1]+=a[r][d]*wv.y;
        acc[r][2]+=a[r][d]*wv.z; acc[r][3]+=a[r][d]*wv.w;
      }
    }
  }
  float4 bv = *(const float4*)&b_in[f0 + colg*4];
  #pragma unroll
  for (int r=0;r<4;r++){
    float4 z;
    z.x = fmaxf(acc[r][0]+bv.x, 0.f);
    z.y = fmaxf(acc[r][1]+bv.y, 0.f);
    z.z = fmaxf(acc[r][2]+bv.z, 0.f);
    z.w = fmaxf(acc[r][3]+bv.w, 0.f);
    *(float4*)&Z[(size_t)(tok0+tokg*4+r)*TDFF + f0 + colg*4] = z;
  }
}

// ---------------------------------------------------------------------------
// K3: out = mask_v * LN1(Hn + Z @ W_out^T + b_out)
// ---------------------------------------------------------------------------
__global__ __launch_bounds__(256) void ffn2_kernel(
    const float* __restrict__ Z, const float* __restrict__ W_out,
    const float* __restrict__ b_out, const float* __restrict__ Hn,
    const float* __restrict__ gain1, const float* __restrict__ bias1,
    const float* __restrict__ mask_v, float* __restrict__ out)
{
  const int tid  = threadIdx.x;
  const int tok0 = blockIdx.x * 32;
  __shared__ float A[32][128];
  __shared__ float Wt[128][128];

  const int tokg = tid>>5, colg = tid&31;
  float acc[4][4] = {};

  for (int c = 0; c < 4; ++c){
    __syncthreads();
    for (int t = tid; t < 32*32; t += 256){
      int row = t>>5, i4 = t&31;
      *(float4*)&A[row][i4*4] = *(const float4*)&Z[(size_t)(tok0+row)*TDFF + c*128 + i4*4];
    }
    for (int t = tid; t < 128*32; t += 256){
      int j = t & 127, i4 = t >> 7;
      float4 w = *(const float4*)&W_out[(size_t)j*TDFF + c*128 + i4*4];
      Wt[i4*4+0][j]=w.x; Wt[i4*4+1][j]=w.y; Wt[i4*4+2][j]=w.z; Wt[i4*4+3][j]=w.w;
    }
    __syncthreads();
    for (int i = 0; i < 128; i += 4){
      float a[4][4];
      #pragma unroll
      for (int r=0;r<4;r++){
        float4 tv=*(const float4*)&A[tokg*4+r][i];
        a[r][0]=tv.x;a[r][1]=tv.y;a[r][2]=tv.z;a[r][3]=tv.w;
      }
      #pragma unroll
      for (int d=0; d<4; ++d){
        float4 wv = *(const float4*)&Wt[i+d][colg*4];
        #pragma unroll
        for (int r=0;r<4;r++){
          acc[r][0]+=a[r][d]*wv.x; acc[r][1]+=a[r][d]*wv.y;
          acc[r][2]+=a[r][d]*wv.z; acc[r][3]+=a[r][d]*wv.w;
        }
      }
    }
  }

  float4 bo = *(const float4*)&b_out[colg*4];
  float4 g  = *(const float4*)&gain1[colg*4];
  float4 bb = *(const float4*)&bias1[colg*4];
  #pragma unroll
  for (int r=0;r<4;r++){
    int tok = tok0 + tokg*4 + r;
    float4 hn = *(const float4*)&Hn[(size_t)tok*TH + colg*4];
    float x0 = acc[r][0]+bo.x+hn.x;
    float x1 = acc[r][1]+bo.y+hn.y;
    float x2 = acc[r][2]+bo.z+hn.z;
    float x3 = acc[r][3]+bo.w+hn.w;
    float s1 = x0+x1+x2+x3;
    float s2 = x0*x0+x1*x1+x2*x2+x3*x3;
    #pragma unroll
    for (int m=16;m>=1;m>>=1){ s1 += __shfl_xor(s1,m,32); s2 += __shfl_xor(s2,m,32); }
    float mu  = s1*(1.f/128.f);
    float var = (s2 - 128.f*mu*mu)*(1.f/127.f);
    float inv = 1.f/(sqrtf(var+LN_EPS)+LN_EPS);
    float mv  = mask_v[tok];
    float4 y;
    y.x = mv*(g.x*(x0-mu)*inv + bb.x);
    y.y = mv*(g.y*(x1-mu)*inv + bb.y);
    y.z = mv*(g.z*(x2-mu)*inv + bb.z);
    y.w = mv*(g.w*(x3-mu)*inv + bb.w);
    *(float4*)&out[(size_t)tok*TH + colg*4] = y;
  }
}

// ---------------------------------------------------------------------------
extern "C" void kernel_launch(void* const* d_in, const int* in_sizes, int n_in,
                              void* d_out, int out_size, void* d_ws, size_t ws_size,
                              hipStream_t stream)
{
  const float* h_v         = (const float*)d_in[0];
  const float* h_e         = (const float*)d_in[1];
  const float* mask_v      = (const float*)d_in[2];
  const float* mask_attend = (const float*)d_in[3];
  const float* W_Q   = (const float*)d_in[4];
  const float* W_K   = (const float*)d_in[5];
  const float* W_V   = (const float*)d_in[6];
  const float* W_O   = (const float*)d_in[7];
  const float* gain0 = (const float*)d_in[8];
  const float* bias0 = (const float*)d_in[9];
  const float* gain1 = (const float*)d_in[10];
  const float* bias1 = (const float*)d_in[11];
  const float* W_in  = (const float*)d_in[12];
  const float* b_in  = (const float*)d_in[13];
  const float* W_out = (const float*)d_in[14];
  const float* b_out = (const float*)d_in[15];

  float* out = (float*)d_out;
  float* Hn  = (float*)d_ws;                    // 8000*128 f32
  float* Z   = Hn + (size_t)NTOK*TH;            // 8000*512 f32
  // Wc2 (128 KB) aliased into the head of Z: written by K0, read by K1,
  // then legally overwritten by ffn1 (stream-ordered after K1 completes).
  unsigned short* Wc2 = (unsigned short*)Z;

  conv_weights_kernel<<<256, 256, 0, stream>>>(W_K, W_V, Wc2);
  attn_kernel<<<NTOK, 256, 0, stream>>>(h_v, h_e, mask_attend, W_Q, Wc2,
                                        W_O, gain0, bias0, Hn);
  ffn1_kernel<<<dim3(NTOK/32, TDFF/128), 256, 0, stream>>>(Hn, W_in, b_in, Z);
  ffn2_kernel<<<NTOK/32, 256, 0, stream>>>(Z, W_out, b_out, Hn, gain1, bias1,
                                           mask_v, out);
}

// Round 4
// 199.375 us; speedup vs baseline: 3.5834x; 1.6845x over previous
//
#include <hip/hip_runtime.h>
#include <math.h>

#define TB 4
#define TN 2000
#define TK 30
#define TH 128
#define TNIN 256
#define TDFF 512
#define NTOK (TB*TN)
#define TBATCH 4   // tokens per attn block

typedef __attribute__((ext_vector_type(8))) short short8v;
typedef __attribute__((ext_vector_type(4))) unsigned short ushort4v;
typedef __attribute__((ext_vector_type(4))) float f32x4;

constexpr float LN_EPS = 1e-6f;
constexpr float NEG_INF = -3.402823466e38f;
constexpr float INV_SQRT_D = 0.17677669529663687f;  // 1/sqrt(32)

// round-to-nearest-even f32 -> bf16
static __device__ __forceinline__ unsigned short f2bf(float f) {
  unsigned u = __float_as_uint(f);
  u = u + 0x7fffu + ((u >> 16) & 1u);
  return (unsigned short)(u >> 16);
}
static __device__ __forceinline__ float bf2f(unsigned short s) {
  return __uint_as_float(((unsigned)s) << 16);
}

// async global->LDS, 16B per lane
static __device__ __forceinline__ void gload16(const void* gsrc, void* ldst) {
  __builtin_amdgcn_global_load_lds(
      (const __attribute__((address_space(1))) unsigned int*)gsrc,
      (__attribute__((address_space(3))) unsigned int*)ldst, 16, 0, 0);
}

// ---------------------------------------------------------------------------
// K0: weight prep.
//  idx <  65536 : Wc2 bf16 MFMA-fragment-linear (as R3, verified):
//    ((kk*16+n)*64+lane)*8+j = Wc[n*16+(lane&15)][kk*32+(lane>>4)*8+j],
//    Wc[r][c] = r<128 ? W_K[r][c] : W_V[r-128][c]
//  65536..81919 : Wqt[i][j] = W_Q[j][i]  (f32, coalesced reads)
//  81920..98303 : Wot[i][j] = W_O[j][i]
// ---------------------------------------------------------------------------
__global__ void conv_weights_kernel(const float* __restrict__ W_K,
                                    const float* __restrict__ W_V,
                                    const float* __restrict__ W_Q,
                                    const float* __restrict__ W_O,
                                    unsigned short* __restrict__ Wc2,
                                    float* __restrict__ Wqt,
                                    float* __restrict__ Wot)
{
  int idx = blockIdx.x * 256 + threadIdx.x;   // 0..98303
  if (idx < 65536) {
    int e = idx >> 3, j = idx & 7;
    int kk = e >> 10, n = (e >> 6) & 15, lane = e & 63;
    int r = n*16 + (lane & 15);
    int c = kk*32 + (lane >> 4)*8 + j;
    float v = (r < TH) ? W_K[(size_t)r*TNIN + c] : W_V[(size_t)(r-TH)*TNIN + c];
    Wc2[idx] = f2bf(v);
  } else if (idx < 81920) {
    int e = idx - 65536; int j = e >> 7, i = e & 127;
    Wqt[i*128 + j] = W_Q[e];
  } else {
    int e = idx - 81920; int j = e >> 7, i = e & 127;
    Wot[i*128 + j] = W_O[e];
  }
}

// ---------------------------------------------------------------------------
// K1: 4-token fused KV-proj (MFMA) -> attention -> W_O -> residual -> LN0.
// grid = 2000 blocks x 512 threads (8 waves). 1 block/CU (148 KB LDS).
// Wave (mh=w>>2, nq=w&3): M-frags mh*4..+4 (tokens 2mh,2mh+1), N-frags nq*4..+4.
// B: Wc2 triple-buffered via global_load_lds, prefetch distance 2.
// A: global->reg->bf16->ds_write, double-buffered, prefetch distance 1.
// ---------------------------------------------------------------------------
__global__ __launch_bounds__(512) void attn_kernel(
    const float* __restrict__ h_v, const float* __restrict__ h_e,
    const float* __restrict__ mask_attend,
    const float* __restrict__ Wqt, const unsigned short* __restrict__ Wc2,
    const float* __restrict__ Wot,
    const float* __restrict__ gain0, const float* __restrict__ bias0,
    float* __restrict__ Hn)
{
  const int bn0  = blockIdx.x * TBATCH;
  const int tid  = threadIdx.x;
  const int wave = tid >> 6;
  const int lane = tid & 63;
  const int lm   = lane & 15;
  const int lgp  = lane >> 4;
  const int mh   = wave >> 2;
  const int nq   = wave & 3;

  __shared__ __align__(16) unsigned short Bl[3][8192];      // 48 KB  B stage
  __shared__ __align__(16) unsigned short Al[2][4][32][32]; // 16 KB  A stage (bf16)
  __shared__ __align__(16) unsigned short Kp[4][32][136];   // 34 KB  Kp row-major
  __shared__ __align__(16) unsigned short Vp[4][128][40];   // 40 KB  Vp col-major
  __shared__ float hv[4][128];
  __shared__ float qv[4][128];
  __shared__ float att[4][4][32];
  __shared__ float ul[4][128];
  __shared__ float xr[4][128];

  // ---- stage h_v rows ----
  if (tid < 128) {
    int tok = tid >> 5, q = tid & 31;
    *(float4*)&hv[tok][q*4] = *(const float4*)&h_v[(size_t)(bn0 + tok)*TH + q*4];
  }
  __syncthreads();

  // ---- Q = h_v @ W_Q^T via transposed Wqt (coalesced) ----
  {
    int tok = tid >> 7, j = tid & 127;
    float a0=0.f, a1=0.f, a2=0.f, a3=0.f;
    #pragma unroll 8
    for (int i = 0; i < TH; i += 4) {
      a0 += Wqt[(i+0)*128 + j] * hv[tok][i+0];
      a1 += Wqt[(i+1)*128 + j] * hv[tok][i+1];
      a2 += Wqt[(i+2)*128 + j] * hv[tok][i+2];
      a3 += Wqt[(i+3)*128 + j] * hv[tok][i+3];
    }
    qv[tok][j] = (a0+a1) + (a2+a3);
  }

  // fence: drain all prior vmem so the staging-queue accounting starts clean
  asm volatile("s_waitcnt vmcnt(0)" ::: "memory");

  // ---- KV projection ----
  // A staging assignment: thread -> (tok, row, 8-col group)
  const int toka = tid >> 7;
  const int rowa = (tid & 127) >> 2;
  const int cga  = tid & 3;
  const int rowc = (rowa > TK-1) ? TK-1 : rowa;   // rows 30,31: junk, never consumed
  const float* aptr = h_e + ((size_t)(bn0 + toka)*TK + rowc)*TNIN + cga*8;

  #define ISSUE_B(K)                                                          \
    { gload16(Wc2 + (size_t)(K)*8192 + tid*8,       &Bl[(K)%3][tid*8]);       \
      gload16(Wc2 + (size_t)(K)*8192 + (tid+512)*8, &Bl[(K)%3][(tid+512)*8]); }

  #define WRITE_A(K, S)                                                       \
    { short8v w;                                                              \
      w[0]=(short)f2bf(ra[S][0].x); w[1]=(short)f2bf(ra[S][0].y);             \
      w[2]=(short)f2bf(ra[S][0].z); w[3]=(short)f2bf(ra[S][0].w);             \
      w[4]=(short)f2bf(ra[S][1].x); w[5]=(short)f2bf(ra[S][1].y);             \
      w[6]=(short)f2bf(ra[S][1].z); w[7]=(short)f2bf(ra[S][1].w);             \
      *(short8v*)&Al[(K)&1][toka][rowa][cga*8] = w; }

  float4 ra[2][2];
  f32x4 acc[4][4] = {};

  // prologue: rA(0); B(0); B(1); rA(1); write A(0)
  ra[0][0] = *(const float4*)(aptr + 0);
  ra[0][1] = *(const float4*)(aptr + 4);
  ISSUE_B(0);
  ISSUE_B(1);
  ra[1][0] = *(const float4*)(aptr + 32);
  ra[1][1] = *(const float4*)(aptr + 36);
  WRITE_A(0, 0);

  #pragma unroll
  for (int k = 0; k < 8; ++k) {
    // guarantee B(k) landed (any load ordering): leave at most B(k+1)+rA(k+1)
    if (k == 7) asm volatile("s_waitcnt vmcnt(0)" ::: "memory");
    else        asm volatile("s_waitcnt vmcnt(4)" ::: "memory");
    __builtin_amdgcn_s_barrier();

    if (k < 6) {
      ISSUE_B(k+2);                                   // -> Bl[(k+2)%3], last read at k-1
      ra[k&1][0] = *(const float4*)(aptr + (k+2)*32); // rA(k+2)
      ra[k&1][1] = *(const float4*)(aptr + (k+2)*32 + 4);
    }

    // compute step k
    short8v af[4];
    #pragma unroll
    for (int m = 0; m < 4; ++m) {
      int mf = mh*4 + m;
      af[m] = *(const short8v*)&Al[k&1][mf>>1][((mf&1)<<4) + lm][lgp*8];
    }
    #pragma unroll
    for (int n = 0; n < 4; ++n) {
      int nf = nq*4 + n;
      short8v b = *(const short8v*)&Bl[k%3][(nf*64 + lane)*8];
      #pragma unroll
      for (int m = 0; m < 4; ++m)
        acc[m][n] = __builtin_amdgcn_mfma_f32_16x16x32_bf16(af[m], b, acc[m][n], 0, 0, 0);
    }

    if (k < 7) WRITE_A(k+1, (k+1)&1);   // consume rA(k+1) -> Al[(k+1)&1]
  }
  #undef ISSUE_B
  #undef WRITE_A

  // ---- C writeout: D row = lgp*4+r, col = lm (verified mapping) ----
  #pragma unroll
  for (int m = 0; m < 4; ++m) {
    int mf = mh*4 + m;
    int tok = mf >> 1;
    int rbase = ((mf&1) << 4) + lgp*4;
    #pragma unroll
    for (int n = 0; n < 4; ++n) {
      int col = nq*64 + n*16 + lm;
      if (nq < 2) {          // Kp (cols 0..127), row-major
        #pragma unroll
        for (int r = 0; r < 4; ++r)
          Kp[tok][rbase + r][col] = f2bf(acc[m][n][r]);
      } else {               // Vp (cols 128..255), col-major
        ushort4v p;
        p[0]=f2bf(acc[m][n][0]); p[1]=f2bf(acc[m][n][1]);
        p[2]=f2bf(acc[m][n][2]); p[3]=f2bf(acc[m][n][3]);
        *(ushort4v*)&Vp[tok][col-128][rbase] = p;
      }
    }
  }
  __syncthreads();

  // ---- logits + softmax (thread = (tok,h,k); 32-lane shfl groups) ----
  {
    int tok = tid >> 7, h = (tid >> 5) & 3, k = tid & 31;
    float s = 0.f;
    #pragma unroll
    for (int j = 0; j < 4; ++j) {
      short8v kf = *(const short8v*)&Kp[tok][k][h*32 + j*8];
      float4 qa  = *(const float4*)&qv[tok][h*32 + j*8];
      float4 qb  = *(const float4*)&qv[tok][h*32 + j*8 + 4];
      s += qa.x*bf2f((unsigned short)kf[0]) + qa.y*bf2f((unsigned short)kf[1])
         + qa.z*bf2f((unsigned short)kf[2]) + qa.w*bf2f((unsigned short)kf[3])
         + qb.x*bf2f((unsigned short)kf[4]) + qb.y*bf2f((unsigned short)kf[5])
         + qb.z*bf2f((unsigned short)kf[6]) + qb.w*bf2f((unsigned short)kf[7]);
    }
    bool ok = (k < TK) && (mask_attend[(size_t)(bn0 + tok)*TK + k] > 0.f);
    float val = ok ? s * INV_SQRT_D : NEG_INF;
    float m = val;
    #pragma unroll
    for (int d = 16; d >= 1; d >>= 1) m = fmaxf(m, __shfl_xor(m, d, 32));
    float e = ok ? expf(val - m) : 0.f;
    float ss = e;
    #pragma unroll
    for (int d = 16; d >= 1; d >>= 1) ss += __shfl_xor(ss, d, 32);
    att[tok][h][k] = e / ss;
  }
  __syncthreads();

  // ---- h_upd = attend @ Vp  (thread = (tok,c); Vp col-major b128 reads) ----
  {
    int tok = tid >> 7, c = tid & 127;
    const float* ar = att[tok][c >> 5];
    float u = 0.f;
    #pragma unroll
    for (int g = 0; g < 4; ++g) {
      short8v vv = *(const short8v*)&Vp[tok][c][g*8];
      #pragma unroll
      for (int r = 0; r < 8; ++r)
        u += ar[g*8 + r] * bf2f((unsigned short)vv[r]);
    }
    ul[tok][c] = u;
  }
  __syncthreads();

  // ---- dh = h_upd @ W_O^T via transposed Wot (coalesced); residual ----
  {
    int tok = tid >> 7, j = tid & 127;
    float a0=0.f, a1=0.f, a2=0.f, a3=0.f;
    #pragma unroll 8
    for (int i = 0; i < TH; i += 4) {
      a0 += Wot[(i+0)*128 + j] * ul[tok][i+0];
      a1 += Wot[(i+1)*128 + j] * ul[tok][i+1];
      a2 += Wot[(i+2)*128 + j] * ul[tok][i+2];
      a3 += Wot[(i+3)*128 + j] * ul[tok][i+3];
    }
    xr[tok][j] = hv[tok][j] + (a0+a1) + (a2+a3);
  }
  __syncthreads();

  // ---- LayerNorm0 (ddof=1, double-eps) : wave w<4 handles token w ----
  if (wave < 4) {
    float x1 = xr[wave][lane], x2 = xr[wave][lane + 64];
    float s1 = x1 + x2, s2 = x1*x1 + x2*x2;
    #pragma unroll
    for (int d = 32; d >= 1; d >>= 1) { s1 += __shfl_xor(s1, d); s2 += __shfl_xor(s2, d); }
    float mu  = s1 * (1.f/128.f);
    float var = (s2 - 128.f*mu*mu) * (1.f/127.f);
    float inv = 1.f/(sqrtf(var + LN_EPS) + LN_EPS);
    float h1 = gain0[lane]    *(x1 - mu)*inv + bias0[lane];
    float h2 = gain0[lane+64] *(x2 - mu)*inv + bias0[lane+64];
    Hn[(size_t)(bn0 + wave)*TH + lane]      = h1;
    Hn[(size_t)(bn0 + wave)*TH + lane + 64] = h2;
  }
}

// ---------------------------------------------------------------------------
// K2: Z = relu(Hn @ W_in^T + b_in)   [8000x128]@[128x512]
// ---------------------------------------------------------------------------
__global__ __launch_bounds__(256) void ffn1_kernel(
    const float* __restrict__ Hn, const float* __restrict__ W_in,
    const float* __restrict__ b_in, float* __restrict__ Z)
{
  const int tid  = threadIdx.x;
  const int tok0 = blockIdx.x * 32;
  const int f0   = blockIdx.y * 128;
  __shared__ float A[32][128];
  __shared__ float Wt[128][128];

  for (int t = tid; t < 32*32; t += 256) {
    int row = t >> 5, i4 = t & 31;
    *(float4*)&A[row][i4*4] = *(const float4*)&Hn[(size_t)(tok0+row)*TH + i4*4];
  }
  for (int t = tid; t < 128*32; t += 256) {
    int f = t & 127, i4 = t >> 7;
    float4 w = *(const float4*)&W_in[(size_t)(f0+f)*TH + i4*4];
    Wt[i4*4+0][f]=w.x; Wt[i4*4+1][f]=w.y; Wt[i4*4+2][f]=w.z; Wt[i4*4+3][f]=w.w;
  }
  __syncthreads();

  const int tokg = tid>>5, colg = tid&31;
  float acc[4][4] = {};
  for (int i = 0; i < TH; i += 4){
    float a[4][4];
    #pragma unroll
    for (int r=0;r<4;r++){
      float4 tv=*(const float4*)&A[tokg*4+r][i];
      a[r][0]=tv.x;a[r][1]=tv.y;a[r][2]=tv.z;a[r][3]=tv.w;
    }
    #pragma unroll
    for (int d=0; d<4; ++d){
      float4 wv = *(const float4*)&Wt[i+d][colg*4];
      #pragma unroll
      for (int r=0;r<4;r++){
        acc[r][0]+=a[r][d]*wv.x; acc[r][1]+=a[r][d]*wv.y;
        acc[r][2]+=a[r][d]*wv.z; acc[r][3]+=a[r][d]*wv.w;
      }
    }
  }
  float4 bv = *(const float4*)&b_in[f0 + colg*4];
  #pragma unroll
  for (int r=0;r<4;r++){
    float4 z;
    z.x = fmaxf(acc[r][0]+bv.x, 0.f);
    z.y = fmaxf(acc[r][1]+bv.y, 0.f);
    z.z = fmaxf(acc[r][2]+bv.z, 0.f);
    z.w = fmaxf(acc[r][3]+bv.w, 0.f);
    *(float4*)&Z[(size_t)(tok0+tokg*4+r)*TDFF + f0 + colg*4] = z;
  }
}

// ---------------------------------------------------------------------------
// K3: out = mask_v * LN1(Hn + Z @ W_out^T + b_out)
// ---------------------------------------------------------------------------
__global__ __launch_bounds__(256) void ffn2_kernel(
    const float* __restrict__ Z, const float* __restrict__ W_out,
    const float* __restrict__ b_out, const float* __restrict__ Hn,
    const float* __restrict__ gain1, const float* __restrict__ bias1,
    const float* __restrict__ mask_v, float* __restrict__ out)
{
  const int tid  = threadIdx.x;
  const int tok0 = blockIdx.x * 32;
  __shared__ float A[32][128];
  __shared__ float Wt[128][128];

  const int tokg = tid>>5, colg = tid&31;
  float acc[4][4] = {};

  for (int c = 0; c < 4; ++c){
    __syncthreads();
    for (int t = tid; t < 32*32; t += 256){
      int row = t>>5, i4 = t&31;
      *(float4*)&A[row][i4*4] = *(const float4*)&Z[(size_t)(tok0+row)*TDFF + c*128 + i4*4];
    }
    for (int t = tid; t < 128*32; t += 256){
      int j = t & 127, i4 = t >> 7;
      float4 w = *(const float4*)&W_out[(size_t)j*TDFF + c*128 + i4*4];
      Wt[i4*4+0][j]=w.x; Wt[i4*4+1][j]=w.y; Wt[i4*4+2][j]=w.z; Wt[i4*4+3][j]=w.w;
    }
    __syncthreads();
    for (int i = 0; i < 128; i += 4){
      float a[4][4];
      #pragma unroll
      for (int r=0;r<4;r++){
        float4 tv=*(const float4*)&A[tokg*4+r][i];
        a[r][0]=tv.x;a[r][1]=tv.y;a[r][2]=tv.z;a[r][3]=tv.w;
      }
      #pragma unroll
      for (int d=0; d<4; ++d){
        float4 wv = *(const float4*)&Wt[i+d][colg*4];
        #pragma unroll
        for (int r=0;r<4;r++){
          acc[r][0]+=a[r][d]*wv.x; acc[r][1]+=a[r][d]*wv.y;
          acc[r][2]+=a[r][d]*wv.z; acc[r][3]+=a[r][d]*wv.w;
        }
      }
    }
  }

  float4 bo = *(const float4*)&b_out[colg*4];
  float4 g  = *(const float4*)&gain1[colg*4];
  float4 bb = *(const float4*)&bias1[colg*4];
  #pragma unroll
  for (int r=0;r<4;r++){
    int tok = tok0 + tokg*4 + r;
    float4 hn = *(const float4*)&Hn[(size_t)tok*TH + colg*4];
    float x0 = acc[r][0]+bo.x+hn.x;
    float x1 = acc[r][1]+bo.y+hn.y;
    float x2 = acc[r][2]+bo.z+hn.z;
    float x3 = acc[r][3]+bo.w+hn.w;
    float s1 = x0+x1+x2+x3;
    float s2 = x0*x0+x1*x1+x2*x2+x3*x3;
    #pragma unroll
    for (int m=16;m>=1;m>>=1){ s1 += __shfl_xor(s1,m,32); s2 += __shfl_xor(s2,m,32); }
    float mu  = s1*(1.f/128.f);
    float var = (s2 - 128.f*mu*mu)*(1.f/127.f);
    float inv = 1.f/(sqrtf(var+LN_EPS)+LN_EPS);
    float mv  = mask_v[tok];
    float4 y;
    y.x = mv*(g.x*(x0-mu)*inv + bb.x);
    y.y = mv*(g.y*(x1-mu)*inv + bb.y);
    y.z = mv*(g.z*(x2-mu)*inv + bb.z);
    y.w = mv*(g.w*(x3-mu)*inv + bb.w);
    *(float4*)&out[(size_t)tok*TH + colg*4] = y;
  }
}

// ---------------------------------------------------------------------------
extern "C" void kernel_launch(void* const* d_in, const int* in_sizes, int n_in,
                              void* d_out, int out_size, void* d_ws, size_t ws_size,
                              hipStream_t stream)
{
  const float* h_v         = (const float*)d_in[0];
  const float* h_e         = (const float*)d_in[1];
  const float* mask_v      = (const float*)d_in[2];
  const float* mask_attend = (const float*)d_in[3];
  const float* W_Q   = (const float*)d_in[4];
  const float* W_K   = (const float*)d_in[5];
  const float* W_V   = (const float*)d_in[6];
  const float* W_O   = (const float*)d_in[7];
  const float* gain0 = (const float*)d_in[8];
  const float* bias0 = (const float*)d_in[9];
  const float* gain1 = (const float*)d_in[10];
  const float* bias1 = (const float*)d_in[11];
  const float* W_in  = (const float*)d_in[12];
  const float* b_in  = (const float*)d_in[13];
  const float* W_out = (const float*)d_in[14];
  const float* b_out = (const float*)d_in[15];

  float* out = (float*)d_out;
  float* Hn  = (float*)d_ws;                    // 8000*128 f32
  float* Z   = Hn + (size_t)NTOK*TH;            // 8000*512 f32
  // scratch weights aliased into Z's head (read only by attn, overwritten by ffn1)
  unsigned short* Wc2 = (unsigned short*)Z;              // 128 KB
  float* Wqt = (float*)((char*)Z + 131072);              // 64 KB
  float* Wot = Wqt + 16384;                              // 64 KB

  conv_weights_kernel<<<384, 256, 0, stream>>>(W_K, W_V, W_Q, W_O, Wc2, Wqt, Wot);
  attn_kernel<<<NTOK/TBATCH, 512, 0, stream>>>(h_v, h_e, mask_attend, Wqt, Wc2,
                                               Wot, gain0, bias0, Hn);
  ffn1_kernel<<<dim3(NTOK/32, TDFF/128), 256, 0, stream>>>(Hn, W_in, b_in, Z);
  ffn2_kernel<<<NTOK/32, 256, 0, stream>>>(Z, W_out, b_out, Hn, gain1, bias1,
                                           mask_v, out);
}

// Round 5
// 161.288 us; speedup vs baseline: 4.4296x; 1.2361x over previous
//
#include <hip/hip_runtime.h>
#include <math.h>

#define TB 4
#define TN 2000
#define TK 30
#define TH 128
#define TNIN 256
#define TDFF 512
#define NTOK (TB*TN)
#define TBATCH 4   // tokens per attn block

typedef __attribute__((ext_vector_type(8))) short short8v;
typedef __attribute__((ext_vector_type(4))) float f32x4;

constexpr float LN_EPS = 1e-6f;
constexpr float NEG_INF = -3.402823466e38f;
constexpr float INV_SQRT_D = 0.17677669529663687f;  // 1/sqrt(32)

// round-to-nearest-even f32 -> bf16
static __device__ __forceinline__ unsigned short f2bf(float f) {
  unsigned u = __float_as_uint(f);
  u = u + 0x7fffu + ((u >> 16) & 1u);
  return (unsigned short)(u >> 16);
}
static __device__ __forceinline__ float bf2f(unsigned short s) {
  return __uint_as_float(((unsigned)s) << 16);
}

// async global->LDS, 16B per lane
static __device__ __forceinline__ void gload16(const void* gsrc, void* ldst) {
  __builtin_amdgcn_global_load_lds(
      (const __attribute__((address_space(1))) unsigned int*)gsrc,
      (__attribute__((address_space(3))) unsigned int*)ldst, 16, 0, 0);
}

// ---------------------------------------------------------------------------
// K0: weight prep (unchanged from R4, verified).
// ---------------------------------------------------------------------------
__global__ void conv_weights_kernel(const float* __restrict__ W_K,
                                    const float* __restrict__ W_V,
                                    const float* __restrict__ W_Q,
                                    const float* __restrict__ W_O,
                                    unsigned short* __restrict__ Wc2,
                                    float* __restrict__ Wqt,
                                    float* __restrict__ Wot)
{
  int idx = blockIdx.x * 256 + threadIdx.x;   // 0..98303
  if (idx < 65536) {
    int e = idx >> 3, j = idx & 7;
    int kk = e >> 10, n = (e >> 6) & 15, lane = e & 63;
    int r = n*16 + (lane & 15);
    int c = kk*32 + (lane >> 4)*8 + j;
    float v = (r < TH) ? W_K[(size_t)r*TNIN + c] : W_V[(size_t)(r-TH)*TNIN + c];
    Wc2[idx] = f2bf(v);
  } else if (idx < 81920) {
    int e = idx - 65536; int j = e >> 7, i = e & 127;
    Wqt[i*128 + j] = W_Q[e];
  } else {
    int e = idx - 81920; int j = e >> 7, i = e & 127;
    Wot[i*128 + j] = W_O[e];
  }
}

// ---------------------------------------------------------------------------
// K1: 4-token fused KV-proj (MFMA) -> attention -> W_O -> residual -> LN0.
// grid = 2000 x 512 threads.  LDS ~76 KB -> 2 blocks/CU (the R5 change:
// post-GEMM KV/att/ul/xr overlaid onto the dead GEMM staging buffers).
// ---------------------------------------------------------------------------
__global__ __launch_bounds__(512, 4) void attn_kernel(
    const float* __restrict__ h_v, const float* __restrict__ h_e,
    const float* __restrict__ mask_attend,
    const float* __restrict__ Wqt, const unsigned short* __restrict__ Wc2,
    const float* __restrict__ Wot,
    const float* __restrict__ gain0, const float* __restrict__ bias0,
    float* __restrict__ Hn)
{
  const int bn0  = blockIdx.x * TBATCH;
  const int tid  = threadIdx.x;
  const int wave = tid >> 6;
  const int lane = tid & 63;
  const int lm   = lane & 15;
  const int lgp  = lane >> 4;
  const int mh   = wave >> 2;
  const int nq   = wave & 3;

  // ---- overlaid LDS ----
  // GEMM phase:  Bl [3][8192] us (48KB) | Al [2][4][32][32] us (16KB)
  // tail phase:  KVs[4][32][264] us (66KB) | att 2KB | ul 2KB | xr 2KB
  __shared__ __align__(16) char smem[73728];
  __shared__ float hv[4][128];
  __shared__ float qv[4][128];
  unsigned short* Bl  = (unsigned short*)smem;        // [3][8192]
  unsigned short* Al  = Bl + 3*8192;                  // [2][4][32][32]
  unsigned short* KVs = (unsigned short*)smem;        // [4][32][264]
  float* att = (float*)(smem + 67584);                // [4][4][32]
  float* ul  = (float*)(smem + 69632);                // [4][128]
  float* xr  = (float*)(smem + 71680);                // [4][128]

  // ---- stage h_v rows ----
  if (tid < 128) {
    int tok = tid >> 5, q = tid & 31;
    *(float4*)&hv[tok][q*4] = *(const float4*)&h_v[(size_t)(bn0 + tok)*TH + q*4];
  }
  __syncthreads();

  // ---- Q = h_v @ W_Q^T via transposed Wqt (coalesced) ----
  {
    int tok = tid >> 7, j = tid & 127;
    float a0=0.f, a1=0.f, a2=0.f, a3=0.f;
    #pragma unroll 8
    for (int i = 0; i < TH; i += 4) {
      a0 += Wqt[(i+0)*128 + j] * hv[tok][i+0];
      a1 += Wqt[(i+1)*128 + j] * hv[tok][i+1];
      a2 += Wqt[(i+2)*128 + j] * hv[tok][i+2];
      a3 += Wqt[(i+3)*128 + j] * hv[tok][i+3];
    }
    qv[tok][j] = (a0+a1) + (a2+a3);
  }

  // drain all prior vmem so staging-queue accounting starts clean
  asm volatile("s_waitcnt vmcnt(0)" ::: "memory");

  // ---- KV projection (pipeline identical to R4, verified) ----
  const int toka = tid >> 7;
  const int rowa = (tid & 127) >> 2;
  const int cga  = tid & 3;
  const int rowc = (rowa > TK-1) ? TK-1 : rowa;   // rows 30,31: junk, never consumed
  const float* aptr = h_e + ((size_t)(bn0 + toka)*TK + rowc)*TNIN + cga*8;

  #define ISSUE_B(K)                                                              \
    { gload16(Wc2 + (size_t)(K)*8192 + tid*8,       &Bl[((K)%3)*8192 + tid*8]);   \
      gload16(Wc2 + (size_t)(K)*8192 + (tid+512)*8, &Bl[((K)%3)*8192 + (tid+512)*8]); }

  #define WRITE_A(K, S)                                                       \
    { short8v w;                                                              \
      w[0]=(short)f2bf(ra[S][0].x); w[1]=(short)f2bf(ra[S][0].y);             \
      w[2]=(short)f2bf(ra[S][0].z); w[3]=(short)f2bf(ra[S][0].w);             \
      w[4]=(short)f2bf(ra[S][1].x); w[5]=(short)f2bf(ra[S][1].y);             \
      w[6]=(short)f2bf(ra[S][1].z); w[7]=(short)f2bf(ra[S][1].w);             \
      *(short8v*)&Al[(((K)&1)*4 + toka)*1024 + rowa*32 + cga*8] = w; }

  float4 ra[2][2];
  f32x4 acc[4][4] = {};

  // prologue: rA(0); B(0); B(1); rA(1); write A(0)
  ra[0][0] = *(const float4*)(aptr + 0);
  ra[0][1] = *(const float4*)(aptr + 4);
  ISSUE_B(0);
  ISSUE_B(1);
  ra[1][0] = *(const float4*)(aptr + 32);
  ra[1][1] = *(const float4*)(aptr + 36);
  WRITE_A(0, 0);

  #pragma unroll
  for (int k = 0; k < 8; ++k) {
    if (k == 7) asm volatile("s_waitcnt vmcnt(0)" ::: "memory");
    else        asm volatile("s_waitcnt vmcnt(4)" ::: "memory");
    __builtin_amdgcn_s_barrier();

    if (k < 6) {
      ISSUE_B(k+2);
      ra[k&1][0] = *(const float4*)(aptr + (k+2)*32);
      ra[k&1][1] = *(const float4*)(aptr + (k+2)*32 + 4);
    }

    short8v af[4];
    #pragma unroll
    for (int m = 0; m < 4; ++m) {
      int mf = mh*4 + m;
      af[m] = *(const short8v*)&Al[((k&1)*4 + (mf>>1))*1024 + (((mf&1)<<4) + lm)*32 + lgp*8];
    }
    #pragma unroll
    for (int n = 0; n < 4; ++n) {
      int nf = nq*4 + n;
      short8v b = *(const short8v*)&Bl[(k%3)*8192 + (nf*64 + lane)*8];
      #pragma unroll
      for (int m = 0; m < 4; ++m)
        acc[m][n] = __builtin_amdgcn_mfma_f32_16x16x32_bf16(af[m], b, acc[m][n], 0, 0, 0);
    }

    if (k < 7) WRITE_A(k+1, (k+1)&1);
  }
  #undef ISSUE_B
  #undef WRITE_A

  // all Bl/Al reads done in every wave before KVs overlays the same bytes
  __syncthreads();

  // ---- C writeout: D row = lgp*4+r, col = lm (verified mapping) ----
  #pragma unroll
  for (int m = 0; m < 4; ++m) {
    int mf = mh*4 + m;
    int tok = mf >> 1;
    int rbase = ((mf&1) << 4) + lgp*4;
    #pragma unroll
    for (int n = 0; n < 4; ++n) {
      int col = nq*64 + n*16 + lm;
      #pragma unroll
      for (int r = 0; r < 4; ++r)
        KVs[(tok*32 + rbase + r)*264 + col] = f2bf(acc[m][n][r]);
    }
  }
  __syncthreads();

  // ---- logits + softmax (thread = (tok,h,k); 32-lane shfl groups) ----
  {
    int tok = tid >> 7, h = (tid >> 5) & 3, k = tid & 31;
    float s = 0.f;
    #pragma unroll
    for (int j = 0; j < 4; ++j) {
      short8v kf = *(const short8v*)&KVs[(tok*32 + k)*264 + h*32 + j*8];
      float4 qa  = *(const float4*)&qv[tok][h*32 + j*8];
      float4 qb  = *(const float4*)&qv[tok][h*32 + j*8 + 4];
      s += qa.x*bf2f((unsigned short)kf[0]) + qa.y*bf2f((unsigned short)kf[1])
         + qa.z*bf2f((unsigned short)kf[2]) + qa.w*bf2f((unsigned short)kf[3])
         + qb.x*bf2f((unsigned short)kf[4]) + qb.y*bf2f((unsigned short)kf[5])
         + qb.z*bf2f((unsigned short)kf[6]) + qb.w*bf2f((unsigned short)kf[7]);
    }
    bool ok = (k < TK) && (mask_attend[(size_t)(bn0 + tok)*TK + k] > 0.f);
    float val = ok ? s * INV_SQRT_D : NEG_INF;
    float m = val;
    #pragma unroll
    for (int d = 16; d >= 1; d >>= 1) m = fmaxf(m, __shfl_xor(m, d, 32));
    float e = ok ? expf(val - m) : 0.f;
    float ss = e;
    #pragma unroll
    for (int d = 16; d >= 1; d >>= 1) ss += __shfl_xor(ss, d, 32);
    att[(tok*4 + h)*32 + k] = e / ss;
  }
  __syncthreads();

  // ---- h_upd = attend @ Vp  (thread=(tok,c); per-k coalesced row reads) ----
  {
    int tok = tid >> 7, c = tid & 127;
    const float* ar = &att[(tok*4 + (c >> 5))*32];
    const unsigned short* vb = &KVs[tok*32*264 + 128 + c];
    float u = 0.f;
    #pragma unroll
    for (int k = 0; k < TK; ++k)
      u += ar[k] * bf2f(vb[k*264]);
    ul[tok*128 + c] = u;
  }
  __syncthreads();

  // ---- dh = h_upd @ W_O^T via transposed Wot (coalesced); residual ----
  {
    int tok = tid >> 7, j = tid & 127;
    float a0=0.f, a1=0.f, a2=0.f, a3=0.f;
    #pragma unroll 8
    for (int i = 0; i < TH; i += 4) {
      a0 += Wot[(i+0)*128 + j] * ul[tok*128 + i+0];
      a1 += Wot[(i+1)*128 + j] * ul[tok*128 + i+1];
      a2 += Wot[(i+2)*128 + j] * ul[tok*128 + i+2];
      a3 += Wot[(i+3)*128 + j] * ul[tok*128 + i+3];
    }
    xr[tok*128 + j] = hv[tok][j] + (a0+a1) + (a2+a3);
  }
  __syncthreads();

  // ---- LayerNorm0 (ddof=1, double-eps): wave w<4 handles token w ----
  if (wave < 4) {
    float x1 = xr[wave*128 + lane], x2 = xr[wave*128 + lane + 64];
    float s1 = x1 + x2, s2 = x1*x1 + x2*x2;
    #pragma unroll
    for (int d = 32; d >= 1; d >>= 1) { s1 += __shfl_xor(s1, d); s2 += __shfl_xor(s2, d); }
    float mu  = s1 * (1.f/128.f);
    float var = (s2 - 128.f*mu*mu) * (1.f/127.f);
    float inv = 1.f/(sqrtf(var + LN_EPS) + LN_EPS);
    float h1 = gain0[lane]    *(x1 - mu)*inv + bias0[lane];
    float h2 = gain0[lane+64] *(x2 - mu)*inv + bias0[lane+64];
    Hn[(size_t)(bn0 + wave)*TH + lane]      = h1;
    Hn[(size_t)(bn0 + wave)*TH + lane + 64] = h2;
  }
}

// ---------------------------------------------------------------------------
// K2: Z = relu(Hn @ W_in^T + b_in)   [8000x128]@[128x512]
// ---------------------------------------------------------------------------
__global__ __launch_bounds__(256) void ffn1_kernel(
    const float* __restrict__ Hn, const float* __restrict__ W_in,
    const float* __restrict__ b_in, float* __restrict__ Z)
{
  const int tid  = threadIdx.x;
  const int tok0 = blockIdx.x * 32;
  const int f0   = blockIdx.y * 128;
  __shared__ float A[32][128];
  __shared__ float Wt[128][128];

  for (int t = tid; t < 32*32; t += 256) {
    int row = t >> 5, i4 = t & 31;
    *(float4*)&A[row][i4*4] = *(const float4*)&Hn[(size_t)(tok0+row)*TH + i4*4];
  }
  for (int t = tid; t < 128*32; t += 256) {
    int f = t & 127, i4 = t >> 7;
    float4 w = *(const float4*)&W_in[(size_t)(f0+f)*TH + i4*4];
    Wt[i4*4+0][f]=w.x; Wt[i4*4+1][f]=w.y; Wt[i4*4+2][f]=w.z; Wt[i4*4+3][f]=w.w;
  }
  __syncthreads();

  const int tokg = tid>>5, colg = tid&31;
  float acc[4][4] = {};
  for (int i = 0; i < TH; i += 4){
    float a[4][4];
    #pragma unroll
    for (int r=0;r<4;r++){
      float4 tv=*(const float4*)&A[tokg*4+r][i];
      a[r][0]=tv.x;a[r][1]=tv.y;a[r][2]=tv.z;a[r][3]=tv.w;
    }
    #pragma unroll
    for (int d=0; d<4; ++d){
      float4 wv = *(const float4*)&Wt[i+d][colg*4];
      #pragma unroll
      for (int r=0;r<4;r++){
        acc[r][0]+=a[r][d]*wv.x; acc[r][1]+=a[r][d]*wv.y;
        acc[r][2]+=a[r][d]*wv.z; acc[r][3]+=a[r][d]*wv.w;
      }
    }
  }
  float4 bv = *(const float4*)&b_in[f0 + colg*4];
  #pragma unroll
  for (int r=0;r<4;r++){
    float4 z;
    z.x = fmaxf(acc[r][0]+bv.x, 0.f);
    z.y = fmaxf(acc[r][1]+bv.y, 0.f);
    z.z = fmaxf(acc[r][2]+bv.z, 0.f);
    z.w = fmaxf(acc[r][3]+bv.w, 0.f);
    *(float4*)&Z[(size_t)(tok0+tokg*4+r)*TDFF + f0 + colg*4] = z;
  }
}

// ---------------------------------------------------------------------------
// K3: out = mask_v * LN1(Hn + Z @ W_out^T + b_out)
// ---------------------------------------------------------------------------
__global__ __launch_bounds__(256) void ffn2_kernel(
    const float* __restrict__ Z, const float* __restrict__ W_out,
    const float* __restrict__ b_out, const float* __restrict__ Hn,
    const float* __restrict__ gain1, const float* __restrict__ bias1,
    const float* __restrict__ mask_v, float* __restrict__ out)
{
  const int tid  = threadIdx.x;
  const int tok0 = blockIdx.x * 32;
  __shared__ float A[32][128];
  __shared__ float Wt[128][128];

  const int tokg = tid>>5, colg = tid&31;
  float acc[4][4] = {};

  for (int c = 0; c < 4; ++c){
    __syncthreads();
    for (int t = tid; t < 32*32; t += 256){
      int row = t>>5, i4 = t&31;
      *(float4*)&A[row][i4*4] = *(const float4*)&Z[(size_t)(tok0+row)*TDFF + c*128 + i4*4];
    }
    for (int t = tid; t < 128*32; t += 256){
      int j = t & 127, i4 = t >> 7;
      float4 w = *(const float4*)&W_out[(size_t)j*TDFF + c*128 + i4*4];
      Wt[i4*4+0][j]=w.x; Wt[i4*4+1][j]=w.y; Wt[i4*4+2][j]=w.z; Wt[i4*4+3][j]=w.w;
    }
    __syncthreads();
    for (int i = 0; i < 128; i += 4){
      float a[4][4];
      #pragma unroll
      for (int r=0;r<4;r++){
        float4 tv=*(const float4*)&A[tokg*4+r][i];
        a[r][0]=tv.x;a[r][1]=tv.y;a[r][2]=tv.z;a[r][3]=tv.w;
      }
      #pragma unroll
      for (int d=0; d<4; ++d){
        float4 wv = *(const float4*)&Wt[i+d][colg*4];
        #pragma unroll
        for (int r=0;r<4;r++){
          acc[r][0]+=a[r][d]*wv.x; acc[r][1]+=a[r][d]*wv.y;
          acc[r][2]+=a[r][d]*wv.z; acc[r][3]+=a[r][d]*wv.w;
        }
      }
    }
  }

  float4 bo = *(const float4*)&b_out[colg*4];
  float4 g  = *(const float4*)&gain1[colg*4];
  float4 bb = *(const float4*)&bias1[colg*4];
  #pragma unroll
  for (int r=0;r<4;r++){
    int tok = tok0 + tokg*4 + r;
    float4 hn = *(const float4*)&Hn[(size_t)tok*TH + colg*4];
    float x0 = acc[r][0]+bo.x+hn.x;
    float x1 = acc[r][1]+bo.y+hn.y;
    float x2 = acc[r][2]+bo.z+hn.z;
    float x3 = acc[r][3]+bo.w+hn.w;
    float s1 = x0+x1+x2+x3;
    float s2 = x0*x0+x1*x1+x2*x2+x3*x3;
    #pragma unroll
    for (int m=16;m>=1;m>>=1){ s1 += __shfl_xor(s1,m,32); s2 += __shfl_xor(s2,m,32); }
    float mu  = s1*(1.f/128.f);
    float var = (s2 - 128.f*mu*mu)*(1.f/127.f);
    float inv = 1.f/(sqrtf(var+LN_EPS)+LN_EPS);
    float mv  = mask_v[tok];
    float4 y;
    y.x = mv*(g.x*(x0-mu)*inv + bb.x);
    y.y = mv*(g.y*(x1-mu)*inv + bb.y);
    y.z = mv*(g.z*(x2-mu)*inv + bb.z);
    y.w = mv*(g.w*(x3-mu)*inv + bb.w);
    *(float4*)&out[(size_t)tok*TH + colg*4] = y;
  }
}

// ---------------------------------------------------------------------------
extern "C" void kernel_launch(void* const* d_in, const int* in_sizes, int n_in,
                              void* d_out, int out_size, void* d_ws, size_t ws_size,
                              hipStream_t stream)
{
  const float* h_v         = (const float*)d_in[0];
  const float* h_e         = (const float*)d_in[1];
  const float* mask_v      = (const float*)d_in[2];
  const float* mask_attend = (const float*)d_in[3];
  const float* W_Q   = (const float*)d_in[4];
  const float* W_K   = (const float*)d_in[5];
  const float* W_V   = (const float*)d_in[6];
  const float* W_O   = (const float*)d_in[7];
  const float* gain0 = (const float*)d_in[8];
  const float* bias0 = (const float*)d_in[9];
  const float* gain1 = (const float*)d_in[10];
  const float* bias1 = (const float*)d_in[11];
  const float* W_in  = (const float*)d_in[12];
  const float* b_in  = (const float*)d_in[13];
  const float* W_out = (const float*)d_in[14];
  const float* b_out = (const float*)d_in[15];

  float* out = (float*)d_out;
  float* Hn  = (float*)d_ws;                    // 8000*128 f32
  float* Z   = Hn + (size_t)NTOK*TH;            // 8000*512 f32
  unsigned short* Wc2 = (unsigned short*)Z;              // 128 KB (aliased, legal)
  float* Wqt = (float*)((char*)Z + 131072);              // 64 KB
  float* Wot = Wqt + 16384;                              // 64 KB

  conv_weights_kernel<<<384, 256, 0, stream>>>(W_K, W_V, W_Q, W_O, Wc2, Wqt, Wot);
  attn_kernel<<<NTOK/TBATCH, 512, 0, stream>>>(h_v, h_e, mask_attend, Wqt, Wc2,
                                               Wot, gain0, bias0, Hn);
  ffn1_kernel<<<dim3(NTOK/32, TDFF/128), 256, 0, stream>>>(Hn, W_in, b_in, Z);
  ffn2_kernel<<<NTOK/32, 256, 0, stream>>>(Z, W_out, b_out, Hn, gain1, bias1,
                                           mask_v, out);
}